// Round 5
// baseline (118.761 us; speedup 1.0000x reference)
//
#include <hip/hip_runtime.h>

#define NB 4096

typedef __attribute__((ext_vector_type(8))) short s8v;   // 8 bf16 (4 VGPR)
typedef __attribute__((ext_vector_type(4))) float f4v;   // MFMA acc

// workspace layout (bytes, 16B-aligned)
#define XB_OFF  0u           // 784*4096*2 bf16     =  6,422,528
#define H1B_OFF 6422528u     // 169*4096*16*2 bf16  = 22,151,168
#define H2B_OFF 28573696u    // 25*4096*32*2 bf16   =  6,553,600
#define W2B_OFF 35127296u    // 25*4*8*2*64*8*2     =  1,638,400
#define B2R_OFF 36765696u    // 25*32*4*4           =     12,800
#define W1B_OFF 36778496u    // 169*4*64*8*2        =    692,224
#define B1R_OFF 37470720u    // 169*16*4*4          =     43,264
#define WFB_OFF 37513984u    // 25*8*64*8*2         =    204,800
// end 37,718,784

__device__ __forceinline__ unsigned short f2bf(float f) {
  unsigned int u = __builtin_bit_cast(unsigned int, f);
  u += 0x7fffu + ((u >> 16) & 1u);
  return (unsigned short)(u >> 16);
}

// ---------------------------------------------------------------------------
// prep1 (R15): only what lc1 needs -- x-transpose + w1b + b1r.  grid 1812.
//  [0,1600)      x -> xB (784,4096) bf16 (32c x 64n tiles, LDS restage)
//  [1600,1769)   w1 -> w1b  [pos169][cv4][lane64][t8]  (lc1 B-frags)
//  [1769,1812)   b1 -> b1r  [pos169][o16][cv4] f32
__global__ __launch_bounds__(256) void k_prep1(const float* __restrict__ x,
                                               const float* __restrict__ w1,
                                               const float* __restrict__ b1,
                                               short* __restrict__ xB,
                                               short* __restrict__ w1b,
                                               float* __restrict__ b1r) {
  const int bx = blockIdx.x;
  if (bx < 1600) {
    __shared__ float t2[64][33];
    const int c0 = (bx % 25) * 32;
    const int n0 = (bx / 25) * 64;
    const int tx = threadIdx.x & 31, ty = threadIdx.x >> 5;
    const int c = c0 + tx;
    #pragma unroll
    for (int i = 0; i < 64; i += 8)
      if (c < 784) t2[ty + i][tx] = x[(n0 + ty + i) * 784 + c];
    __syncthreads();
    const int cl = threadIdx.x >> 3;
    const int ns = (threadIdx.x & 7) * 8;
    if (c0 + cl < 784) {
      unsigned short v[8];
      #pragma unroll
      for (int q = 0; q < 8; q++) v[q] = f2bf(t2[ns + q][cl]);
      *reinterpret_cast<s8v*>(&xB[(c0 + cl) * NB + n0 + ns]) =
          *reinterpret_cast<const s8v*>(v);
    }
  } else if (bx < 1769) {
    const int q = (bx - 1600) * 256 + threadIdx.x;  // 43,264 groups of 8
    const int l = q & 63;
    const int cv = (q >> 6) & 3;
    const int pos = q >> 8;
    const int o = l & 15;
    const int i = pos / 13, j = pos % 13;
    const int dy = cv >> 1, dx = cv & 1;
    unsigned short v[8];
    #pragma unroll
    for (int t = 0; t < 8; t++) {
      const int k = (l >> 4) * 8 + t;
      float f = 0.f;
      if (k < 16) {
        const int py = k >> 2, px = k & 3;
        const int ky = py - dy, kx = px - dx;
        if (ky >= 0 && ky < 3 && kx >= 0 && kx < 3)
          f = w1[(o * 9 + ky * 3 + kx) * 676 + (2 * i + dy) * 26 + 2 * j + dx];
      }
      v[t] = f2bf(f);
    }
    *reinterpret_cast<s8v*>(&w1b[q * 8]) = *reinterpret_cast<const s8v*>(v);
  } else {
    const int idx = (bx - 1769) * 256 + threadIdx.x;  // 10,816 elems
    if (idx < 10816) {
      const int cv = idx & 3;
      const int o = (idx >> 2) & 15;
      const int pos = idx >> 6;
      const int i = pos / 13, j = pos % 13;
      b1r[idx] = b1[(o * 26 + 2 * i + (cv >> 1)) * 26 + 2 * j + (cv & 1)];
    }
  }
}

// ---------------------------------------------------------------------------
// LC1 via bf16 MFMA 16x16x32 (R12 compute body) + fused prep2 tail blocks.
// R16: FLAT grid with XCD-pinned nt.  f < 2704: nt = (f&7)*2 + ((f>>3)&1),
// pos = f>>4.  With round-robin block->XCD dispatch (f%8), all 169 pos-blocks
// of an nt-pair land on one XCD: the 2x401KB xB slices stay L2-resident
// (4MB/XCD) -> xB L3 traffic 21.6 -> ~6.4 MB.  Pure index permutation;
// arithmetic bit-identical.
//   f in [2704, 3168): pid = f - 2704:
//     [0,400)   w2 -> w2b  [pos25][cv4][s8][ot2][lane64][t8]
//     400       b2 -> b2r  [pos25][o32][cv4] f32
//     [401,451) f1w -> wfb [s25][jt8][lane64][t8]
__global__ __launch_bounds__(256, 3) void k_lc1(const short* __restrict__ xB,
                                                const short* __restrict__ w1b,
                                                const float* __restrict__ b1r,
                                                short* __restrict__ h1b,
                                                const float* __restrict__ w2,
                                                const float* __restrict__ b2,
                                                const float* __restrict__ f1w,
                                                short* __restrict__ w2b,
                                                float* __restrict__ b2r,
                                                short* __restrict__ wfb) {
  __shared__ short sx[16 * 264 + 16 + 8];       // swizzled [k16][n256]
  __shared__ unsigned short ush[256 * 24];      // [n256 pitch24][o16]
  const int f = blockIdx.x;

  if (f >= 2704) {   // ---- fused prep2 blocks ----
    const int pid = f - 2704;
    if (pid < 400) {
      const int q = pid * 256 + threadIdx.x;  // 102,400 groups of 8
      const int l = q & 63;
      const int ot = (q >> 6) & 1;
      const int s = (q >> 7) & 7;
      const int cv = (q >> 10) & 3;
      const int pos = q >> 12;
      const int o = ot * 16 + (l & 15);
      const int dy = cv >> 1, dx = cv & 1;
      const int I = pos / 5, J = pos % 5;
      unsigned short v[8];
      #pragma unroll
      for (int t = 0; t < 8; t++) {
        const int k = s * 32 + (l >> 4) * 8 + t;
        const int w = k >> 4, c = k & 15;
        const int py = w >> 2, px = w & 3;
        const int ky = py - dy, kx = px - dx;
        float f2 = 0.f;
        if (ky >= 0 && ky < 3 && kx >= 0 && kx < 3)
          f2 = w2[((o * 16 + c) * 9 + ky * 3 + kx) * 121 +
                  (2 * I + dy) * 11 + (2 * J + dx)];
        v[t] = f2bf(f2);
      }
      *reinterpret_cast<s8v*>(&w2b[q * 8]) = *reinterpret_cast<const s8v*>(v);
    } else if (pid == 400) {
      for (int q = threadIdx.x; q < 3200; q += 256) {
        const int pos = q >> 7;
        const int r = q & 127;
        const int o = r >> 2, cv = r & 3;
        const int I = pos / 5, J = pos % 5;
        b2r[q] = b2[o * 121 + (2 * I + (cv >> 1)) * 11 + 2 * J + (cv & 1)];
      }
    } else if (pid < 451) {
      const int q = (pid - 401) * 256 + threadIdx.x;  // 12,800 groups of 8
      const int l = q & 63;
      const int jt = (q >> 6) & 7;
      const int s = q >> 9;
      const int j = jt * 16 + (l & 15);
      unsigned short v[8];
      #pragma unroll
      for (int t = 0; t < 8; t++) {
        const int o = (l >> 4) * 8 + t;
        v[t] = f2bf(f1w[(o * 25 + s) * 128 + j]);
      }
      *reinterpret_cast<s8v*>(&wfb[q * 8]) = *reinterpret_cast<const s8v*>(v);
    }
    return;
  }

  // ---- lc1 proper: XCD-pinned decode ----
  const int nt = (f & 7) * 2 + ((f >> 3) & 1);  // 0..15, pinned per XCD
  const int pos = f >> 4;                        // 0..168
  const int i = pos / 13, j = pos % 13;
  const int tid = threadIdx.x;
  const int l = tid & 63;
  const int wv = tid >> 6;
  const int lm = l & 15, kg = l >> 4;
  const int n0b = nt * 256;

  #pragma unroll
  for (int rr = 0; rr < 2; rr++) {
    const int idx = rr * 256 + tid;
    const int row = idx >> 5, seg = idx & 31;
    const int grow = (2 * i + (row >> 2)) * 28 + (2 * j + (row & 3));
    *reinterpret_cast<s8v*>(&sx[row * 264 + ((row >> 3) & 1) * 16 + seg * 8]) =
        *reinterpret_cast<const s8v*>(&xB[grow * NB + n0b + seg * 8]);
  }

  s8v bf[4];
  #pragma unroll
  for (int cv = 0; cv < 4; cv++)
    bf[cv] = *reinterpret_cast<const s8v*>(w1b + ((pos * 4 + cv) * 64 + l) * 8);
  const float4 bias = *reinterpret_cast<const float4*>(b1r + (pos * 16 + lm) * 4);
  __syncthreads();

  f4v acc[4][4];
  #pragma unroll
  for (int a = 0; a < 4; a++)
    #pragma unroll
    for (int cv = 0; cv < 4; cv++) acc[a][cv] = (f4v){0.f, 0.f, 0.f, 0.f};

  #pragma unroll
  for (int a = 0; a < 4; a++) {
    const int nl = wv * 64 + a * 16 + lm;
    s8v av = (s8v){0, 0, 0, 0, 0, 0, 0, 0};
    if (kg < 2) {
      #pragma unroll
      for (int t = 0; t < 8; t++) {
        const int k = kg * 8 + t;
        av[t] = sx[k * 264 + ((k >> 3) & 1) * 16 + nl];
      }
    }
    #pragma unroll
    for (int cv = 0; cv < 4; cv++)
      acc[a][cv] =
          __builtin_amdgcn_mfma_f32_16x16x32_bf16(av, bf[cv], acc[a][cv], 0, 0, 0);
  }

  #pragma unroll
  for (int a = 0; a < 4; a++) {
    #pragma unroll
    for (int reg = 0; reg < 4; reg++) {
      const int nl = wv * 64 + a * 16 + kg * 4 + reg;
      const float v =
          fmaxf(fmaxf(acc[a][0][reg] + bias.x, acc[a][1][reg] + bias.y),
                fmaxf(acc[a][2][reg] + bias.z, acc[a][3][reg] + bias.w));
      ush[nl * 24 + lm] = f2bf(fmaxf(v, 0.f));
    }
  }
  __syncthreads();

  short* dst = h1b + (pos * 4096 + n0b + tid) * 16;
  const unsigned short* src = ush + tid * 24;
  *reinterpret_cast<s8v*>(dst) = *reinterpret_cast<const s8v*>(src);
  *reinterpret_cast<s8v*>(dst + 8) = *reinterpret_cast<const s8v*>(src + 8);
}

// ---------------------------------------------------------------------------
// LC2 via bf16 MFMA 16x16x32.  h1B -> h2b [pos25][n4096][o32] bf16.
// R15 ot-split (32KB slab, 4 blocks/CU) + R16 XCD-pinned flat grid:
// f in [0,800): nt = (f&7)*2 + ((f>>3)&1), q = f>>4, pos = q>>1, ot = q&1.
// All 50 (pos,ot) blocks of an nt-pair land on one XCD -> the 2x1.35MB h1b
// slices stay L2-resident; issued A-traffic served from L2 instead of L3.
__global__ __launch_bounds__(256, 4) void k_lc2(const short* __restrict__ h1b,
                                                const short* __restrict__ w2b,
                                                const float* __restrict__ b2r,
                                                short* __restrict__ h2b) {
  __shared__ short sb[16384];  // [cv4][s8][lane64][t8] = 32 KB (this ot)
  const int f = blockIdx.x;
  const int nt = (f & 7) * 2 + ((f >> 3) & 1);  // 0..15, pinned per XCD
  const int q = f >> 4;                          // 0..49
  const int pos = q >> 1;
  const int ot = q & 1;
  const int I = pos / 5, J = pos % 5;
  const int tid = threadIdx.x;
  const int l = tid & 63;
  const int wave = tid >> 6;
  const int nw = nt * 256 + wave * 64;          // wave's 64-n base
  const int kg = l >> 4;
  const int lm = l & 15;
  const int c0 = (kg & 1) * 8;
  const int whalf = kg >> 1;

  // stage this ot's half-slab: 8 coalesced s8v per thread
  const short* wsrc = w2b + pos * 32768;
  #pragma unroll
  for (int r8 = 0; r8 < 8; r8++) {
    const int idx = r8 * 256 + tid;   // 0..2047 = (r=cv*8+s)*64 + ll
    const int r = idx >> 6;
    const int ll = idx & 63;
    *reinterpret_cast<s8v*>(&sb[idx * 8]) =
        *reinterpret_cast<const s8v*>(&wsrc[((r * 2 + ot) * 64 + ll) * 8]);
  }
  __syncthreads();

  f4v acc[4][4];
  #pragma unroll
  for (int a = 0; a < 4; a++)
    #pragma unroll
    for (int cv = 0; cv < 4; cv++)
      acc[a][cv] = (f4v){0.f, 0.f, 0.f, 0.f};

  #pragma unroll
  for (int s = 0; s < 8; s++) {
    const int wdw = s * 2 + whalf;
    const int py = wdw >> 2, px = wdw & 3;
    const int p = (2 * I + py) * 13 + (2 * J + px);
    const int abase = (p * 4096 + nw + lm) * 16 + c0;
    s8v bf[4];
    #pragma unroll
    for (int cv = 0; cv < 4; cv++)
      bf[cv] = *reinterpret_cast<const s8v*>(
          &sb[((cv * 8 + s) * 64 + l) * 8]);
    #pragma unroll
    for (int a = 0; a < 4; a++) {
      const s8v av = *reinterpret_cast<const s8v*>(h1b + abase + a * 256);
      #pragma unroll
      for (int cv = 0; cv < 4; cv++)
        acc[a][cv] =
            __builtin_amdgcn_mfma_f32_16x16x32_bf16(av, bf[cv], acc[a][cv], 0, 0, 0);
    }
  }

  const int o = ot * 16 + lm;
  const float4 bias = *reinterpret_cast<const float4*>(b2r + (pos * 32 + o) * 4);
  #pragma unroll
  for (int a = 0; a < 4; a++) {
    const int nb = nw + a * 16 + kg * 4;
    #pragma unroll
    for (int reg = 0; reg < 4; reg++) {
      const float v =
          fmaxf(fmaxf(acc[a][0][reg] + bias.x, acc[a][1][reg] + bias.y),
                fmaxf(acc[a][2][reg] + bias.z, acc[a][3][reg] + bias.w));
      h2b[(pos * 4096 + nb + reg) * 32 + o] = (short)f2bf(fmaxf(v, 0.f));
    }
  }
}

// ---------------------------------------------------------------------------
// fused FC1(relu)+FC2 via bf16 MFMA.  h2b (K'-permuted) -> out (N,10).
// grid 256 (n-tile 16), block 256 = 4 waves; wave w covers j-tiles {2w,2w+1}.
__global__ __launch_bounds__(256) void k_fc(const short* __restrict__ h2b,
                                            const short* __restrict__ wfb,
                                            const float* __restrict__ f1b,
                                            const float* __restrict__ f2w,
                                            const float* __restrict__ f2b,
                                            float* __restrict__ out) {
  __shared__ float sh3[128 * 17];   // [j128][n16 pad17]
  __shared__ float swf2[128 * 12];  // fc2 weights, 12-padded
  __shared__ float sb1[128];
  const int tid = threadIdx.x;
  const int l = tid & 63;
  const int w = tid >> 6;
  const int lm = l & 15, kg = l >> 4;
  const int n0 = blockIdx.x * 16;
  const int jt0 = w * 2;

  for (int idx = tid; idx < 1536; idx += 256) {
    const int kk = idx / 12, f = idx % 12;
    swf2[idx] = (f < 10) ? f2w[kk * 10 + f] : 0.f;
  }
  if (tid < 128) sb1[tid] = f1b[tid];

  f4v acc0 = (f4v){0.f, 0.f, 0.f, 0.f};
  f4v acc1 = (f4v){0.f, 0.f, 0.f, 0.f};

  #pragma unroll
  for (int s = 0; s < 25; s++) {
    const s8v av = *reinterpret_cast<const s8v*>(
        h2b + (s * 4096 + n0 + lm) * 32 + kg * 8);
    const s8v b0 = *reinterpret_cast<const s8v*>(
        wfb + ((s * 8 + jt0) * 64 + l) * 8);
    const s8v b1v = *reinterpret_cast<const s8v*>(
        wfb + ((s * 8 + jt0 + 1) * 64 + l) * 8);
    acc0 = __builtin_amdgcn_mfma_f32_16x16x32_bf16(av, b0, acc0, 0, 0, 0);
    acc1 = __builtin_amdgcn_mfma_f32_16x16x32_bf16(av, b1v, acc1, 0, 0, 0);
  }
  __syncthreads();

  #pragma unroll
  for (int q = 0; q < 2; q++) {
    const f4v a = q ? acc1 : acc0;
    const int j = (jt0 + q) * 16 + lm;
    #pragma unroll
    for (int reg = 0; reg < 4; reg++)
      sh3[j * 17 + kg * 4 + reg] = fmaxf(a[reg] + sb1[j], 0.f);
  }
  __syncthreads();

  if (tid < 160) {
    const int oo = tid >> 4, nn = tid & 15;
    float s = f2b[oo];
    for (int j = 0; j < 128; j++)
      s += sh3[j * 17 + nn] * swf2[j * 12 + oo];
    out[(n0 + nn) * 10 + oo] = s;
  }
}

// ---------------------------------------------------------------------------
extern "C" void kernel_launch(void* const* d_in, const int* in_sizes, int n_in,
                              void* d_out, int out_size, void* d_ws,
                              size_t ws_size, hipStream_t stream) {
  const float* x   = (const float*)d_in[0];
  const float* w1  = (const float*)d_in[1];
  const float* b1  = (const float*)d_in[2];
  const float* w2  = (const float*)d_in[3];
  const float* b2  = (const float*)d_in[4];
  const float* f1w = (const float*)d_in[5];
  const float* f1b = (const float*)d_in[6];
  const float* f2w = (const float*)d_in[7];
  const float* f2b = (const float*)d_in[8];
  float* out = (float*)d_out;
  char* ws = (char*)d_ws;
  short* xB  = (short*)(ws + XB_OFF);
  short* h1b = (short*)(ws + H1B_OFF);
  short* h2b = (short*)(ws + H2B_OFF);
  short* w2b = (short*)(ws + W2B_OFF);
  float* b2r = (float*)(ws + B2R_OFF);
  short* w1b = (short*)(ws + W1B_OFF);
  float* b1r = (float*)(ws + B1R_OFF);
  short* wfb = (short*)(ws + WFB_OFF);

  k_prep1<<<1812, 256, 0, stream>>>(x, w1, b1, xB, w1b, b1r);
  k_lc1<<<3168, 256, 0, stream>>>(xB, w1b, b1r, h1b,
                                  w2, b2, f1w, w2b, b2r, wfb);
  k_lc2<<<800, 256, 0, stream>>>(h1b, w2b, b2r, h2b);
  k_fc<<<256, 256, 0, stream>>>(h2b, wfb, f1b, f2w, f2b, out);
}

// Round 7
// 116.802 us; speedup vs baseline: 1.0168x; 1.0168x over previous
//
#include <hip/hip_runtime.h>

#define NB 4096

typedef __attribute__((ext_vector_type(8))) short s8v;   // 8 bf16 (4 VGPR)
typedef __attribute__((ext_vector_type(4))) float f4v;   // MFMA acc

// workspace layout (bytes, 16B-aligned)
#define XB_OFF  0u           // 784*4096*2 bf16     =  6,422,528
#define H1B_OFF 6422528u     // 169*4096*16*2 bf16  = 22,151,168
#define H2B_OFF 28573696u    // 25*4096*32*2 bf16   =  6,553,600
#define W2B_OFF 35127296u    // 25*4*8*2*64*8*2     =  1,638,400
#define B2R_OFF 36765696u    // 25*32*4*4           =     12,800
#define W1B_OFF 36778496u    // 169*4*64*8*2        =    692,224
#define B1R_OFF 37470720u    // 169*16*4*4          =     43,264
#define WFB_OFF 37513984u    // 25*8*64*8*2         =    204,800
// end 37,718,784

__device__ __forceinline__ unsigned short f2bf(float f) {
  unsigned int u = __builtin_bit_cast(unsigned int, f);
  u += 0x7fffu + ((u >> 16) & 1u);
  return (unsigned short)(u >> 16);
}

// ---------------------------------------------------------------------------
// prep (R12: weight gathers vectorized -- 8 contiguous bf16 per thread, one
// s8v store; grid 2263 blocks):
//  [0,1600)      x -> xB (784,4096) bf16 (32c x 64n tiles, LDS restage)
//  [1600,1769)   w1 -> w1b  [pos169][cv4][lane64][t8]  (lc1 B-frags)
//  [1769,1812)   b1 -> b1r  [pos169][o16][cv4] f32
//  [1812,2212)   w2 -> w2b  [pos25][cv4][s8][ot2][lane64][t8] (lc2 B-frags)
//  2212          b2 -> b2r  [pos25][o32][cv4] f32
//  [2213,2263)   f1w -> wfb [s25][jt8][lane64][t8]  (fc1 B-frags, k=o*25+s)
__global__ __launch_bounds__(256) void k_prep(const float* __restrict__ x,
                                              const float* __restrict__ w1,
                                              const float* __restrict__ b1,
                                              const float* __restrict__ w2,
                                              const float* __restrict__ b2,
                                              const float* __restrict__ f1w,
                                              short* __restrict__ xB,
                                              short* __restrict__ w1b,
                                              float* __restrict__ b1r,
                                              short* __restrict__ w2b,
                                              float* __restrict__ b2r,
                                              short* __restrict__ wfb) {
  const int bx = blockIdx.x;
  if (bx < 1600) {
    __shared__ float t2[64][33];
    const int c0 = (bx % 25) * 32;
    const int n0 = (bx / 25) * 64;
    const int tx = threadIdx.x & 31, ty = threadIdx.x >> 5;
    const int c = c0 + tx;
    #pragma unroll
    for (int i = 0; i < 64; i += 8)
      if (c < 784) t2[ty + i][tx] = x[(n0 + ty + i) * 784 + c];
    __syncthreads();
    const int cl = threadIdx.x >> 3;
    const int ns = (threadIdx.x & 7) * 8;
    if (c0 + cl < 784) {
      unsigned short v[8];
      #pragma unroll
      for (int q = 0; q < 8; q++) v[q] = f2bf(t2[ns + q][cl]);
      *reinterpret_cast<s8v*>(&xB[(c0 + cl) * NB + n0 + ns]) =
          *reinterpret_cast<const s8v*>(v);
    }
  } else if (bx < 1769) {
    const int q = (bx - 1600) * 256 + threadIdx.x;  // 43,264 groups of 8
    const int l = q & 63;
    const int cv = (q >> 6) & 3;
    const int pos = q >> 8;
    const int o = l & 15;
    const int i = pos / 13, j = pos % 13;
    const int dy = cv >> 1, dx = cv & 1;
    unsigned short v[8];
    #pragma unroll
    for (int t = 0; t < 8; t++) {
      const int k = (l >> 4) * 8 + t;
      float f = 0.f;
      if (k < 16) {
        const int py = k >> 2, px = k & 3;
        const int ky = py - dy, kx = px - dx;
        if (ky >= 0 && ky < 3 && kx >= 0 && kx < 3)
          f = w1[(o * 9 + ky * 3 + kx) * 676 + (2 * i + dy) * 26 + 2 * j + dx];
      }
      v[t] = f2bf(f);
    }
    *reinterpret_cast<s8v*>(&w1b[q * 8]) = *reinterpret_cast<const s8v*>(v);
  } else if (bx < 1812) {
    const int idx = (bx - 1769) * 256 + threadIdx.x;  // 10,816 elems
    if (idx < 10816) {
      const int cv = idx & 3;
      const int o = (idx >> 2) & 15;
      const int pos = idx >> 6;
      const int i = pos / 13, j = pos % 13;
      b1r[idx] = b1[(o * 26 + 2 * i + (cv >> 1)) * 26 + 2 * j + (cv & 1)];
    }
  } else if (bx < 2212) {
    const int q = (bx - 1812) * 256 + threadIdx.x;  // 102,400 groups of 8
    const int l = q & 63;
    const int ot = (q >> 6) & 1;
    const int s = (q >> 7) & 7;
    const int cv = (q >> 10) & 3;
    const int pos = q >> 12;
    const int o = ot * 16 + (l & 15);
    const int dy = cv >> 1, dx = cv & 1;
    const int I = pos / 5, J = pos % 5;
    unsigned short v[8];
    #pragma unroll
    for (int t = 0; t < 8; t++) {
      const int k = s * 32 + (l >> 4) * 8 + t;
      const int w = k >> 4, c = k & 15;
      const int py = w >> 2, px = w & 3;
      const int ky = py - dy, kx = px - dx;
      float f = 0.f;
      if (ky >= 0 && ky < 3 && kx >= 0 && kx < 3)
        f = w2[((o * 16 + c) * 9 + ky * 3 + kx) * 121 +
               (2 * I + dy) * 11 + (2 * J + dx)];
      v[t] = f2bf(f);
    }
    *reinterpret_cast<s8v*>(&w2b[q * 8]) = *reinterpret_cast<const s8v*>(v);
  } else if (bx == 2212) {
    for (int q = threadIdx.x; q < 3200; q += 256) {
      const int pos = q >> 7;
      const int r = q & 127;
      const int o = r >> 2, cv = r & 3;
      const int I = pos / 5, J = pos % 5;
      b2r[q] = b2[o * 121 + (2 * I + (cv >> 1)) * 11 + 2 * J + (cv & 1)];
    }
  } else {
    const int q = (bx - 2213) * 256 + threadIdx.x;  // 12,800 groups of 8
    const int l = q & 63;
    const int jt = (q >> 6) & 7;
    const int s = q >> 9;
    const int j = jt * 16 + (l & 15);
    unsigned short v[8];
    #pragma unroll
    for (int t = 0; t < 8; t++) {
      const int o = (l >> 4) * 8 + t;
      v[t] = f2bf(f1w[(o * 25 + s) * 128 + j]);
    }
    *reinterpret_cast<s8v*>(&wfb[q * 8]) = *reinterpret_cast<const s8v*>(v);
  }
}

// ---------------------------------------------------------------------------
// LC1 via bf16 MFMA 16x16x32 (K=16 real + 16 zero).  xB (784,N) bf16 ->
// h1B (169,N,16c) bf16.  LDS-staged input + write-combined output.
__global__ __launch_bounds__(256, 3) void k_lc1(const short* __restrict__ xB,
                                                const short* __restrict__ w1b,
                                                const float* __restrict__ b1r,
                                                short* __restrict__ h1b) {
  __shared__ short sx[16 * 264 + 16 + 8];       // swizzled [k16][n256]
  __shared__ unsigned short ush[256 * 24];      // [n256 pitch24][o16]
  const int pos = blockIdx.y;
  const int i = pos / 13, j = pos % 13;
  const int tid = threadIdx.x;
  const int l = tid & 63;
  const int wv = tid >> 6;
  const int lm = l & 15, kg = l >> 4;
  const int n0b = blockIdx.x * 256;

  #pragma unroll
  for (int rr = 0; rr < 2; rr++) {
    const int idx = rr * 256 + tid;
    const int row = idx >> 5, seg = idx & 31;
    const int grow = (2 * i + (row >> 2)) * 28 + (2 * j + (row & 3));
    *reinterpret_cast<s8v*>(&sx[row * 264 + ((row >> 3) & 1) * 16 + seg * 8]) =
        *reinterpret_cast<const s8v*>(&xB[grow * NB + n0b + seg * 8]);
  }

  s8v bf[4];
  #pragma unroll
  for (int cv = 0; cv < 4; cv++)
    bf[cv] = *reinterpret_cast<const s8v*>(w1b + ((pos * 4 + cv) * 64 + l) * 8);
  const float4 bias = *reinterpret_cast<const float4*>(b1r + (pos * 16 + lm) * 4);
  __syncthreads();

  f4v acc[4][4];
  #pragma unroll
  for (int a = 0; a < 4; a++)
    #pragma unroll
    for (int cv = 0; cv < 4; cv++) acc[a][cv] = (f4v){0.f, 0.f, 0.f, 0.f};

  #pragma unroll
  for (int a = 0; a < 4; a++) {
    const int nl = wv * 64 + a * 16 + lm;
    s8v av = (s8v){0, 0, 0, 0, 0, 0, 0, 0};
    if (kg < 2) {
      #pragma unroll
      for (int t = 0; t < 8; t++) {
        const int k = kg * 8 + t;
        av[t] = sx[k * 264 + ((k >> 3) & 1) * 16 + nl];
      }
    }
    #pragma unroll
    for (int cv = 0; cv < 4; cv++)
      acc[a][cv] =
          __builtin_amdgcn_mfma_f32_16x16x32_bf16(av, bf[cv], acc[a][cv], 0, 0, 0);
  }

  #pragma unroll
  for (int a = 0; a < 4; a++) {
    #pragma unroll
    for (int reg = 0; reg < 4; reg++) {
      const int nl = wv * 64 + a * 16 + kg * 4 + reg;
      const float v =
          fmaxf(fmaxf(acc[a][0][reg] + bias.x, acc[a][1][reg] + bias.y),
                fmaxf(acc[a][2][reg] + bias.z, acc[a][3][reg] + bias.w));
      ush[nl * 24 + lm] = f2bf(fmaxf(v, 0.f));
    }
  }
  __syncthreads();

  short* dst = h1b + (pos * 4096 + n0b + tid) * 16;
  const unsigned short* src = ush + tid * 24;
  *reinterpret_cast<s8v*>(dst) = *reinterpret_cast<const s8v*>(src);
  *reinterpret_cast<s8v*>(dst + 8) = *reinterpret_cast<const s8v*>(src + 8);
}

// ---------------------------------------------------------------------------
// LC2 via bf16 MFMA 16x16x32.  h1B -> h2b [pos25][n4096][o32] bf16.
// full 64KB pos B-slab staged in LDS once (coalesced, one barrier,
// conflict-free b128 readback).  LDS 64KB -> 2 blocks/CU.  grid (32 nt, 25).
__global__ __launch_bounds__(256, 2) void k_lc2(const short* __restrict__ h1b,
                                                const short* __restrict__ w2b,
                                                const float* __restrict__ b2r,
                                                short* __restrict__ h2b) {
  __shared__ short sb[32768];  // [cv4][s8][ot2][lane64][t8] = 64 KB
  const int pos = blockIdx.y;
  const int I = pos / 5, J = pos % 5;
  const int tid = threadIdx.x;
  const int l = tid & 63;
  const int wave = tid >> 6;
  const int wm = wave >> 1, ot = wave & 1;
  const int nw = blockIdx.x * 128 + wm * 64;   // wave's 64-n base
  const int kg = l >> 4;
  const int lm = l & 15;
  const int c0 = (kg & 1) * 8;
  const int whalf = kg >> 1;

  // stage the pos's full B slab: 16 coalesced s8v per thread
  const short* wsrc = w2b + pos * 32768;
  #pragma unroll
  for (int r = 0; r < 16; r++) {
    const int idx = r * 256 + tid;
    *reinterpret_cast<s8v*>(&sb[idx * 8]) =
        *reinterpret_cast<const s8v*>(&wsrc[idx * 8]);
  }
  __syncthreads();

  f4v acc[4][4];
  #pragma unroll
  for (int a = 0; a < 4; a++)
    #pragma unroll
    for (int cv = 0; cv < 4; cv++)
      acc[a][cv] = (f4v){0.f, 0.f, 0.f, 0.f};

  #pragma unroll
  for (int s = 0; s < 8; s++) {
    const int wdw = s * 2 + whalf;
    const int py = wdw >> 2, px = wdw & 3;
    const int p = (2 * I + py) * 13 + (2 * J + px);
    const int abase = (p * 4096 + nw + lm) * 16 + c0;
    s8v av[4];
    #pragma unroll
    for (int a = 0; a < 4; a++)
      av[a] = *reinterpret_cast<const s8v*>(h1b + abase + a * 256);
    #pragma unroll
    for (int cv = 0; cv < 4; cv++) {
      const s8v bf = *reinterpret_cast<const s8v*>(
          &sb[(((cv * 8 + s) * 2 + ot) * 64 + l) * 8]);
      #pragma unroll
      for (int a = 0; a < 4; a++)
        acc[a][cv] =
            __builtin_amdgcn_mfma_f32_16x16x32_bf16(av[a], bf, acc[a][cv], 0, 0, 0);
    }
  }

  const int o = ot * 16 + lm;
  const float4 bias = *reinterpret_cast<const float4*>(b2r + (pos * 32 + o) * 4);
  #pragma unroll
  for (int a = 0; a < 4; a++) {
    const int nb = nw + a * 16 + kg * 4;
    #pragma unroll
    for (int reg = 0; reg < 4; reg++) {
      const float v =
          fmaxf(fmaxf(acc[a][0][reg] + bias.x, acc[a][1][reg] + bias.y),
                fmaxf(acc[a][2][reg] + bias.z, acc[a][3][reg] + bias.w));
      h2b[(pos * 4096 + nb + reg) * 32 + o] = (short)f2bf(fmaxf(v, 0.f));
    }
  }
}

// ---------------------------------------------------------------------------
// fused FC1(relu)+FC2 via bf16 MFMA.  h2b (K'-permuted) -> out (N,10).
// grid 256 (n-tile 16), block 256 = 4 waves; wave w covers j-tiles {2w,2w+1}.
__global__ __launch_bounds__(256) void k_fc(const short* __restrict__ h2b,
                                            const short* __restrict__ wfb,
                                            const float* __restrict__ f1b,
                                            const float* __restrict__ f2w,
                                            const float* __restrict__ f2b,
                                            float* __restrict__ out) {
  __shared__ float sh3[128 * 17];   // [j128][n16 pad17]
  __shared__ float swf2[128 * 12];  // fc2 weights, 12-padded
  __shared__ float sb1[128];
  const int tid = threadIdx.x;
  const int l = tid & 63;
  const int w = tid >> 6;
  const int lm = l & 15, kg = l >> 4;
  const int n0 = blockIdx.x * 16;
  const int jt0 = w * 2;

  for (int idx = tid; idx < 1536; idx += 256) {
    const int kk = idx / 12, f = idx % 12;
    swf2[idx] = (f < 10) ? f2w[kk * 10 + f] : 0.f;
  }
  if (tid < 128) sb1[tid] = f1b[tid];

  f4v acc0 = (f4v){0.f, 0.f, 0.f, 0.f};
  f4v acc1 = (f4v){0.f, 0.f, 0.f, 0.f};

  #pragma unroll
  for (int s = 0; s < 25; s++) {
    const s8v av = *reinterpret_cast<const s8v*>(
        h2b + (s * 4096 + n0 + lm) * 32 + kg * 8);
    const s8v b0 = *reinterpret_cast<const s8v*>(
        wfb + ((s * 8 + jt0) * 64 + l) * 8);
    const s8v b1v = *reinterpret_cast<const s8v*>(
        wfb + ((s * 8 + jt0 + 1) * 64 + l) * 8);
    acc0 = __builtin_amdgcn_mfma_f32_16x16x32_bf16(av, b0, acc0, 0, 0, 0);
    acc1 = __builtin_amdgcn_mfma_f32_16x16x32_bf16(av, b1v, acc1, 0, 0, 0);
  }
  __syncthreads();

  #pragma unroll
  for (int q = 0; q < 2; q++) {
    const f4v a = q ? acc1 : acc0;
    const int j = (jt0 + q) * 16 + lm;
    #pragma unroll
    for (int reg = 0; reg < 4; reg++)
      sh3[j * 17 + kg * 4 + reg] = fmaxf(a[reg] + sb1[j], 0.f);
  }
  __syncthreads();

  if (tid < 160) {
    const int oo = tid >> 4, nn = tid & 15;
    float s = f2b[oo];
    for (int j = 0; j < 128; j++)
      s += sh3[j * 17 + nn] * swf2[j * 12 + oo];
    out[(n0 + nn) * 10 + oo] = s;
  }
}

// ---------------------------------------------------------------------------
extern "C" void kernel_launch(void* const* d_in, const int* in_sizes, int n_in,
                              void* d_out, int out_size, void* d_ws,
                              size_t ws_size, hipStream_t stream) {
  const float* x   = (const float*)d_in[0];
  const float* w1  = (const float*)d_in[1];
  const float* b1  = (const float*)d_in[2];
  const float* w2  = (const float*)d_in[3];
  const float* b2  = (const float*)d_in[4];
  const float* f1w = (const float*)d_in[5];
  const float* f1b = (const float*)d_in[6];
  const float* f2w = (const float*)d_in[7];
  const float* f2b = (const float*)d_in[8];
  float* out = (float*)d_out;
  char* ws = (char*)d_ws;
  short* xB  = (short*)(ws + XB_OFF);
  short* h1b = (short*)(ws + H1B_OFF);
  short* h2b = (short*)(ws + H2B_OFF);
  short* w2b = (short*)(ws + W2B_OFF);
  float* b2r = (float*)(ws + B2R_OFF);
  short* w1b = (short*)(ws + W1B_OFF);
  float* b1r = (float*)(ws + B1R_OFF);
  short* wfb = (short*)(ws + WFB_OFF);

  k_prep<<<2263, 256, 0, stream>>>(x, w1, b1, w2, b2, f1w,
                                   xB, w1b, b1r, w2b, b2r, wfb);
  k_lc1<<<dim3(16, 169), 256, 0, stream>>>(xB, w1b, b1r, h1b);
  k_lc2<<<dim3(32, 25), 256, 0, stream>>>(h1b, w2b, b2r, h2b);
  k_fc<<<256, 256, 0, stream>>>(h2b, wfb, f1b, f2w, f2b, out);
}